// Round 11
// baseline (119.066 us; speedup 1.0000x reference)
//
#include <hip/hip_runtime.h>

// B=32 rows, N=8192, K=256. Straight-through estimator forward value
// == hard one-hot-sum + sample_memory (soft terms cancel numerically).
//
// R10 (resubmit after infra timeout): single dispatch, 32 blocks x 1024 thr
// (multi-dispatch variants R4/R6/R7/R9 all lost to dispatch-gap + cold-ws
// cost). Minimal select:
//   - one 12-bit histogram pass (2 group-private copies, bank-shifted)
//   - one block-parallel suffix scan -> crossing bin p12 + residual need
//   - compact the bin's M (~100-250) candidates to LDS
//   - exact rank by direct comparison (key desc, col asc) -- O(M^2)
//     LDS broadcasts spread over 1024 threads, replaces two more
//     hist passes + scans + tie machinery of R5.
// 5 barriers total (R5 had 10), 1 atomic pass (R5 had 3).

#define NROW 32
#define NCOL 8192
#define KSEL 256
#define THREADS 1024
#define H0S 4097          // 4096 bins + 1 pad -> copy 1 shifted by one bank

__device__ __forceinline__ unsigned float_to_key(float f) {
    unsigned u = __float_as_uint(f);
    return (u & 0x80000000u) ? ~u : (u | 0x80000000u);  // monotone
}

__global__ __launch_bounds__(THREADS) void topk_kernel(
    const float* __restrict__ logits, const float* __restrict__ noise,
    const float* __restrict__ mem, float* __restrict__ out)
{
    __shared__ unsigned h0[2 * H0S];          // 32.8 KB, 2 group-private copies
    __shared__ unsigned keyC[8192];           // 32 KB candidate keys
    __shared__ unsigned short colC[8192];     // 16 KB candidate columns
    __shared__ unsigned wp[16];
    __shared__ unsigned sh_d, sh_need, sh_cnt;

    const int tid  = threadIdx.x;
    const int wave = tid >> 6;
    const int lane = tid & 63;
    const int grp  = wave >> 3;               // waves 0-7 -> copy 0, 8-15 -> copy 1
    const int base = blockIdx.x * NCOL + tid * 8;

    // ---- issue all loads first ----
    float4 lg0 = ((const float4*)(logits + base))[0];
    float4 lg1 = ((const float4*)(logits + base))[1];
    float4 no0 = ((const float4*)(noise  + base))[0];
    float4 no1 = ((const float4*)(noise  + base))[1];
    float4 mm0 = ((const float4*)(mem    + base))[0];
    float4 mm1 = ((const float4*)(mem    + base))[1];

    // zero histograms while loads are in flight
    for (int i = tid; i < 2 * H0S; i += THREADS) h0[i] = 0u;

    unsigned key[8];
    key[0] = float_to_key(lg0.x + no0.x + mm0.x * -1000.0f);
    key[1] = float_to_key(lg0.y + no0.y + mm0.y * -1000.0f);
    key[2] = float_to_key(lg0.z + no0.z + mm0.z * -1000.0f);
    key[3] = float_to_key(lg0.w + no0.w + mm0.w * -1000.0f);
    key[4] = float_to_key(lg1.x + no1.x + mm1.x * -1000.0f);
    key[5] = float_to_key(lg1.y + no1.y + mm1.y * -1000.0f);
    key[6] = float_to_key(lg1.z + no1.z + mm1.z * -1000.0f);
    key[7] = float_to_key(lg1.w + no1.w + mm1.w * -1000.0f);
    __syncthreads();                                     // B1

    // ---- 12-bit histogram, group-private ----
    {
        unsigned* h = h0 + grp * H0S;
#pragma unroll
        for (int i = 0; i < 8; ++i) atomicAdd(&h[key[i] >> 20], 1u);
    }
    __syncthreads();                                     // B2

    // ---- suffix scan over 4096 bins: thread t owns bins 4095-4t .. 4092-4t ----
    unsigned need = KSEL;
    const int tb = 4095 - 4 * tid;
    {
        unsigned c[4], tot = 0;
#pragma unroll
        for (int j = 0; j < 4; ++j) {
            const int d = tb - j;
            c[j] = h0[d] + h0[H0S + d];
            tot += c[j];
        }
        unsigned s = tot;
#pragma unroll
        for (int off = 1; off < 64; off <<= 1) {
            unsigned nv = __shfl_up(s, off, 64);
            if (lane >= off) s += nv;
        }
        if (lane == 63) wp[wave] = s;
        if (tid == 0) sh_cnt = 0u;
        __syncthreads();                                 // B3
        unsigned add = 0;
        for (int w = 0; w < wave; ++w) add += wp[w];
        unsigned cum = s + add - tot;                    // count in higher bins
#pragma unroll
        for (int j = 0; j < 4; ++j) {
            const unsigned nc = cum + c[j];
            if (nc >= need && cum < need) { sh_d = (unsigned)(tb - j); sh_need = need - cum; }
            cum = nc;
        }
    }
    __syncthreads();                                     // B4
    const unsigned p12 = sh_d;
    need = sh_need;     // quota inside bin p12; keys in higher bins auto-selected

    // ---- compact bin-p12 candidates (order irrelevant; rank uses key+col) ----
#pragma unroll
    for (int i = 0; i < 8; ++i) {
        if ((key[i] >> 20) == p12) {
            const unsigned slot = atomicAdd(&sh_cnt, 1u);
            keyC[slot] = key[i];
            colC[slot] = (unsigned short)(tid * 8 + i);
        }
    }
    __syncthreads();                                     // B5
    const unsigned M = sh_cnt;

    // ---- emit: exact rank within bin via direct comparison ----
    float o[8];
#pragma unroll
    for (int i = 0; i < 8; ++i) {
        const unsigned k = key[i];
        float sel;
        if ((k >> 20) > p12) {
            sel = 1.0f;
        } else if ((k >> 20) == p12) {
            const unsigned short mycol = (unsigned short)(tid * 8 + i);
            unsigned rk = 0;
            for (unsigned q = 0; q < M; ++q) {            // LDS broadcast reads
                const unsigned kq = keyC[q];
                rk += (kq > k || (kq == k && colC[q] < mycol)) ? 1u : 0u;
            }
            sel = (rk < need) ? 1.0f : 0.0f;
        } else {
            sel = 0.0f;
        }
        o[i] = sel;
    }
    o[0] += mm0.x; o[1] += mm0.y; o[2] += mm0.z; o[3] += mm0.w;
    o[4] += mm1.x; o[5] += mm1.y; o[6] += mm1.z; o[7] += mm1.w;
    ((float4*)(out + base))[0] = make_float4(o[0], o[1], o[2], o[3]);
    ((float4*)(out + base))[1] = make_float4(o[4], o[5], o[6], o[7]);
}

extern "C" void kernel_launch(void* const* d_in, const int* in_sizes, int n_in,
                              void* d_out, int out_size, void* d_ws, size_t ws_size,
                              hipStream_t stream) {
    const float* logits = (const float*)d_in[0];
    const float* noise  = (const float*)d_in[1];
    const float* mem    = (const float*)d_in[2];
    float* out = (float*)d_out;

    topk_kernel<<<NROW, THREADS, 0, stream>>>(logits, noise, mem, out);
}